// Round 12
// baseline (277.379 us; speedup 1.0000x reference)
//
#include <hip/hip_runtime.h>
#include <hip/hip_bf16.h>

// Problem constants
#define B_  2
#define S_  2048
#define D_  1024
#define H_  16
#define HD_ 64
#define M_  4096   // B_*S_

// Inputs/outputs f32; internal compute bf16 MFMA with f32 accumulation.
// ws (24 MB + 45 KB):
//   [0,8)MB  q bf16 (CE-prescaled; attn in-place)
//   [8,16)MB kb bf16
//   [16,24)MB WT bf16: 4 x [1024][1024] ([q CE*g | k g | v g | o plain])
//   +24MB: biasf f32[3][1024], mean f32[4096], rstd f32[4096]
// d_out (16 MB f32) as scratch until the final GEMM:
//   [0,8)MB vT bf16 [bh][d][s]   [8,16)MB kT bf16 [bh][d][s]
// gemm_out reads q + WT[o] (ws), writes d_out directly (vT/kT dead).

typedef __attribute__((ext_vector_type(8))) short short8;
typedef __attribute__((ext_vector_type(4))) float f32x4;

#define CE_ 0.1803368801111204f   // 0.125 * log2(e)
#define SD_ 56                    // padded LDS row stride (shorts)

typedef __attribute__((address_space(1))) const unsigned GU;
typedef __attribute__((address_space(3))) unsigned LU;
static __device__ __forceinline__ void glds16(const void* g, void* l){
  __builtin_amdgcn_global_load_lds((GU*)g, (LU*)l, 16, 0, 0);
}

static __device__ __forceinline__ unsigned short f2bfc(float f){
  union{float f; unsigned u;} c; c.f = f;
  return (unsigned short)((c.u + 0x8000u) >> 16);
}
static __device__ __forceinline__ unsigned pk2bf(float a, float b){
  union{float f; unsigned u;} ca, cb; ca.f=a; cb.f=b;
  return __builtin_amdgcn_perm(cb.u + 0x8000u, ca.u + 0x8000u, 0x07060302u);
}
static __device__ __forceinline__ unsigned pk2bft(float a, float b){
  union{float f; unsigned u;} ca, cb; ca.f=a; cb.f=b;
  return __builtin_amdgcn_perm(cb.u, ca.u, 0x07060302u);
}

// ---------------------------------------------------------------------------
// Merged prep: [0,1024) stats ; [1024,2048) wtrans ; [2048,2096) biasfold
// ---------------------------------------------------------------------------
__global__ __launch_bounds__(256) void prep_kernel(
  const float* __restrict__ data, float* __restrict__ mean, float* __restrict__ rstd,
  const float* __restrict__ Wq, const float* __restrict__ Wk,
  const float* __restrict__ Wv, const float* __restrict__ Wo,
  const float* __restrict__ gq, const float* __restrict__ gk, const float* __restrict__ gv,
  const float* __restrict__ blq, const float* __restrict__ blk, const float* __restrict__ blv,
  const float* __restrict__ bpq, const float* __restrict__ bpk, const float* __restrict__ bpv,
  unsigned short* __restrict__ WT, float* __restrict__ bf)
{
  __shared__ unsigned short tile[64][72];
  __shared__ float red[4][64];
  int bid = blockIdx.x, t = threadIdx.x;
  if (bid < 1024){
    int row = bid*4 + (t>>6);
    int l = t & 63;
    const float4* xr = (const float4*)(data + (size_t)row*D_);
    float s = 0.f, ss = 0.f;
    #pragma unroll
    for (int i=0;i<4;i++){
      float4 v = xr[l + 64*i];
      s  += v.x+v.y+v.z+v.w;
      ss += v.x*v.x+v.y*v.y+v.z*v.z+v.w*v.w;
    }
    #pragma unroll
    for (int m=1;m<64;m<<=1){ s += __shfl_xor(s, m, 64); ss += __shfl_xor(ss, m, 64); }
    if (l==0){
      float me = s*(1.0f/D_);
      float var = ss*(1.0f/D_) - me*me;
      mean[row] = me;
      rstd[row] = rsqrtf(var + 1e-5f);
    }
  } else if (bid < 2048){
    int idx = bid - 1024;
    int z = idx >> 8, rem = idx & 255;
    int k0 = (rem>>4)*64, n0 = (rem&15)*64;
    const float* W = (z==0)?Wq:(z==1)?Wk:(z==2)?Wv:Wo;
    const float* g = (z==0)?gq:(z==1)?gk:(z==2)?gv:(const float*)0;
    unsigned short* out = WT + ((size_t)z<<20);
    {
      int kr = t>>2, c16 = (t&3)*16;
      float gs = g ? g[k0+kr]*((z==0)?CE_:1.0f) : 1.0f;
      const float* src = W + (size_t)(k0+kr)*D_ + n0 + c16;
      float4 w0 = *(const float4*)(src);
      float4 w1 = *(const float4*)(src+4);
      float4 w2 = *(const float4*)(src+8);
      float4 w3 = *(const float4*)(src+12);
      unsigned* tp = (unsigned*)&tile[kr][c16];
      tp[0]=pk2bf(w0.x*gs,w0.y*gs); tp[1]=pk2bf(w0.z*gs,w0.w*gs);
      tp[2]=pk2bf(w1.x*gs,w1.y*gs); tp[3]=pk2bf(w1.z*gs,w1.w*gs);
      tp[4]=pk2bf(w2.x*gs,w2.y*gs); tp[5]=pk2bf(w2.z*gs,w2.w*gs);
      tp[6]=pk2bf(w3.x*gs,w3.y*gs); tp[7]=pk2bf(w3.z*gs,w3.w*gs);
    }
    __syncthreads();
    {
      int nr = t>>2, kc = (t&3)*16;
      union { uint4 v[2]; unsigned short u[16]; } st;
      #pragma unroll
      for (int i=0;i<16;i++) st.u[i] = tile[kc+i][nr];
      unsigned short* dst = out + (size_t)(n0+nr)*D_ + k0 + kc;
      *(uint4*)(dst)     = st.v[0];
      *(uint4*)(dst + 8) = st.v[1];
    }
  } else {
    int idx = bid - 2048;
    int z = idx >> 4, xb = idx & 15;
    const float* W  = (z==0)?Wq:(z==1)?Wk:Wv;
    const float* bl = (z==0)?blq:(z==1)?blk:blv;
    const float* bp = (z==0)?bpq:(z==1)?bpk:bpv;
    int nl = t & 63, kg = t >> 6;
    int n = xb*64 + nl;
    float acc = 0.f;
    for (int k = kg*256; k < (kg+1)*256; k++)
      acc += bl[k] * W[(size_t)k*D_ + n];
    red[kg][nl] = acc;
    __syncthreads();
    if (t < 64){
      int nn = xb*64 + t;
      float v = red[0][t]+red[1][t]+red[2][t]+red[3][t] + bp[nn];
      bf[z*D_ + nn] = (z==0) ? v*CE_ : v;
    }
  }
}

// ---------------------------------------------------------------------------
// Fused QKV GEMM, grid (32,8,3). 128x128 tile. As padded stride-56 (manual LN
// staging); Bs unpadded stride-32 via global_load_lds width=16.
// ---------------------------------------------------------------------------
__global__ __launch_bounds__(256) void gemm_qkv(
  const float* __restrict__ data,
  const unsigned short* __restrict__ WT,
  const float* __restrict__ biasf,
  const float* __restrict__ mean, const float* __restrict__ rstd,
  unsigned short* __restrict__ qv, unsigned short* __restrict__ kb,
  unsigned short* __restrict__ kT, unsigned short* __restrict__ vT)
{
  int z = blockIdx.z;
  const unsigned short* Bt = WT + ((size_t)z<<20);
  const float* bias = biasf + z*D_;
  unsigned short* oN = (z==0)?qv:(z==1)?kb:(unsigned short*)0;
  unsigned short* oT = (z==0)?(unsigned short*)0:(z==1)?kT:vT;

  __shared__ __align__(16) unsigned short As[128*SD_];
  __shared__ __align__(16) unsigned short Bs[128*32];
  int tid = threadIdx.x, w = tid>>6, l = tid&63;
  int m0 = blockIdx.x*128, n0 = blockIdx.y*128;
  int wr = (w>>1)*64, wc = (w&1)*64;
  int lr = l&15, qd = l>>4;
  int srow = tid>>2, scol = (tid&3)*8;

  float rs0 = rstd[m0+srow],    nm0 = -mean[m0+srow]*rs0;
  float rs1 = rstd[m0+srow+64], nm1 = -mean[m0+srow+64]*rs1;

  const unsigned short* gB = Bt + (size_t)(n0 + w*32 + (l>>2))*D_ + (l&3)*8;
  unsigned short* lB0 = &Bs[(w*32)*32];
  unsigned short* lB1 = &Bs[(w*32+16)*32];

  const f32x4 fz = {0.f,0.f,0.f,0.f};
  f32x4 acc[4][4];
  #pragma unroll
  for (int i=0;i<4;i++)
    #pragma unroll
    for (int j=0;j<4;j++) acc[i][j] = fz;

  for (int kk=0; kk<D_; kk+=32){
    __syncthreads();
    glds16(gB + kk,                 lB0);
    glds16(gB + kk + (size_t)16*D_, lB1);
    {
      const float* p0 = data + (size_t)(m0+srow   )*D_ + kk + scol;
      const float* p1 = data + (size_t)(m0+srow+64)*D_ + kk + scol;
      float4 a0 = *(const float4*)(p0), a0b = *(const float4*)(p0+4);
      float4 a1 = *(const float4*)(p1), a1b = *(const float4*)(p1+4);
      uint4 o0, o1;
      o0.x = pk2bf(fmaf(a0.x ,rs0,nm0), fmaf(a0.y ,rs0,nm0));
      o0.y = pk2bf(fmaf(a0.z ,rs0,nm0), fmaf(a0.w ,rs0,nm0));
      o0.z = pk2bf(fmaf(a0b.x,rs0,nm0), fmaf(a0b.y,rs0,nm0));
      o0.w = pk2bf(fmaf(a0b.z,rs0,nm0), fmaf(a0b.w,rs0,nm0));
      o1.x = pk2bf(fmaf(a1.x ,rs1,nm1), fmaf(a1.y ,rs1,nm1));
      o1.y = pk2bf(fmaf(a1.z ,rs1,nm1), fmaf(a1.w ,rs1,nm1));
      o1.z = pk2bf(fmaf(a1b.x,rs1,nm1), fmaf(a1b.y,rs1,nm1));
      o1.w = pk2bf(fmaf(a1b.z,rs1,nm1), fmaf(a1b.w,rs1,nm1));
      *(uint4*)(As + srow*SD_      + scol) = o0;
      *(uint4*)(As + (srow+64)*SD_ + scol) = o1;
    }
    __syncthreads();
    short8 af[4], bfr[4];
    #pragma unroll
    for (int i=0;i<4;i++) af[i]  = *(const short8*)(As + (wr + i*16 + lr)*SD_ + qd*8);
    #pragma unroll
    for (int j=0;j<4;j++) bfr[j] = *(const short8*)(Bs + (wc + j*16 + lr)*32 + qd*8);
    #pragma unroll
    for (int i=0;i<4;i++)
      #pragma unroll
      for (int j=0;j<4;j++)
        acc[i][j] = __builtin_amdgcn_mfma_f32_16x16x32_bf16(af[i], bfr[j], acc[i][j], 0, 0, 0);
  }

  #pragma unroll
  for (int j=0;j<4;j++){
    int n = n0 + wc + j*16 + lr;
    float bias_n = bias[n];
    #pragma unroll
    for (int i=0;i<4;i++){
      int mb = m0 + wr + i*16 + qd*4;
      float v0 = acc[i][j][0] + bias_n;
      float v1 = acc[i][j][1] + bias_n;
      float v2 = acc[i][j][2] + bias_n;
      float v3 = acc[i][j][3] + bias_n;
      if (oN){
        oN[(size_t)(mb+0)*D_ + n] = f2bfc(v0);
        oN[(size_t)(mb+1)*D_ + n] = f2bfc(v1);
        oN[(size_t)(mb+2)*D_ + n] = f2bfc(v2);
        oN[(size_t)(mb+3)*D_ + n] = f2bfc(v3);
      }
      if (oT){
        int bb = mb >> 11, sI = mb & (S_-1);
        int hh = n >> 6,  dd = n & 63;
        uint2 pk; pk.x = pk2bf(v0, v1); pk.y = pk2bf(v2, v3);
        *(uint2*)(oT + (size_t)((bb*H_ + hh)*HD_ + dd)*S_ + sI) = pk;
      }
    }
  }
}

// ---------------------------------------------------------------------------
// Out-projection: C = A(bf16) @ WTo^T + bo, f32 to d_out. Both tiles via glds.
// ---------------------------------------------------------------------------
__global__ __launch_bounds__(256) void gemm_out(
  const unsigned short* __restrict__ A,
  const unsigned short* __restrict__ Bt,
  const float* __restrict__ bo,
  float* __restrict__ Cf)
{
  __shared__ __align__(16) unsigned short As[128*32];
  __shared__ __align__(16) unsigned short Bs[128*32];
  int tid = threadIdx.x, w = tid>>6, l = tid&63;
  int m0 = blockIdx.x*128, n0 = blockIdx.y*128;
  int wr = (w>>1)*64, wc = (w&1)*64;
  int lr = l&15, qd = l>>4;

  const unsigned short* gA = A  + (size_t)(m0 + w*32 + (l>>2))*D_ + (l&3)*8;
  const unsigned short* gB = Bt + (size_t)(n0 + w*32 + (l>>2))*D_ + (l&3)*8;
  unsigned short* lA0 = &As[(w*32)*32];
  unsigned short* lA1 = &As[(w*32+16)*32];
  unsigned short* lB0 = &Bs[(w*32)*32];
  unsigned short* lB1 = &Bs[(w*32+16)*32];

  const f32x4 fz = {0.f,0.f,0.f,0.f};
  f32x4 acc[4][4];
  #pragma unroll
  for (int i=0;i<4;i++)
    #pragma unroll
    for (int j=0;j<4;j++) acc[i][j] = fz;

  for (int kk=0; kk<D_; kk+=32){
    __syncthreads();
    glds16(gA + kk,                 lA0);
    glds16(gA + kk + (size_t)16*D_, lA1);
    glds16(gB + kk,                 lB0);
    glds16(gB + kk + (size_t)16*D_, lB1);
    __syncthreads();
    short8 af[4], bfr[4];
    #pragma unroll
    for (int i=0;i<4;i++) af[i]  = *(const short8*)(As + (wr + i*16 + lr)*32 + qd*8);
    #pragma unroll
    for (int j=0;j<4;j++) bfr[j] = *(const short8*)(Bs + (wc + j*16 + lr)*32 + qd*8);
    #pragma unroll
    for (int i=0;i<4;i++)
      #pragma unroll
      for (int j=0;j<4;j++)
        acc[i][j] = __builtin_amdgcn_mfma_f32_16x16x32_bf16(af[i], bfr[j], acc[i][j], 0, 0, 0);
  }

  #pragma unroll
  for (int j=0;j<4;j++){
    int n = n0 + wc + j*16 + lr;
    float bias_n = bo[n];
    #pragma unroll
    for (int i=0;i<4;i++){
      int mb = m0 + wr + i*16 + qd*4;
      Cf[(size_t)(mb+0)*D_ + n] = acc[i][j][0] + bias_n;
      Cf[(size_t)(mb+1)*D_ + n] = acc[i][j][1] + bias_n;
      Cf[(size_t)(mb+2)*D_ + n] = acc[i][j][2] + bias_n;
      Cf[(size_t)(mb+3)*D_ + n] = acc[i][j][3] + bias_n;
    }
  }
}

// ---------------------------------------------------------------------------
// Fused double Hopfield attention: round-11 structure with gg-SEQUENTIAL
// wave-private P buffer (sP halved: 28672 -> 14336 B; block LDS 57344 ->
// 43008 B -> 3 blocks/CU instead of 2). BK=64, one-tile register prefetch,
// HW exp2, VALU row-sum. In-place on QO (bf16, CE-prescaled). grid (32,16).
// Correctness of gg-sequential store->read->overwrite: per-wave LDS ops
// complete in issue order (in-order DS FIFO), proven in round 10.
// ---------------------------------------------------------------------------
__global__ __launch_bounds__(256) void attn_fused(
  unsigned short* __restrict__ QO,
  const unsigned short* __restrict__ K,
  const unsigned short* __restrict__ KT,
  const unsigned short* __restrict__ VT)
{
  int qt = blockIdx.x;           // 0..31
  int h  = blockIdx.y;           // 0..15
  int b  = qt >> 4;
  int bh = b*H_ + h;
  int tid = threadIdx.x, w = tid>>6, l = tid&63;
  int lr = l&15, qd = l>>4;
  int r8 = tid>>3, c8 = (tid&7)*8;
  int chf = c8>>5, co = c8&31;

  __shared__ __align__(16) unsigned short sK[2][64*SD_];
  __shared__ __align__(16) unsigned short sV[2][64*SD_];
  __shared__ __align__(16) unsigned short sP[4][2][16*SD_];  // gg-sequential

  const f32x4 fz = {0.f,0.f,0.f,0.f};

  unsigned short* Qbase = QO + (size_t)(qt*128 + w*32) * D_ + h*64;
  short8 qf[2][2];
  #pragma unroll
  for (int gg=0; gg<2; gg++)
    #pragma unroll
    for (int hf=0; hf<2; hf++)
      qf[gg][hf] = *(const short8*)(Qbase + (size_t)(gg*16+lr)*D_ + hf*32 + qd*8);

  const unsigned short* Khead = K + (size_t)(b*S_)*D_ + h*64;
  const unsigned short* Vh0 = KT + (size_t)bh*HD_*S_;
  const unsigned short* Vh1 = VT + (size_t)bh*HD_*S_;
  unsigned short* Pw0 = &sP[w][0][0];
  unsigned short* Pw1 = &sP[w][1][0];

  f32x4 oacc[2][4];
  float lac[2];

  // staging registers (software pipeline)
  uint4 kr0, kr1, vr0, vr1;
  {
    kr0 = *(const uint4*)(Khead + (size_t)(r8   )*D_ + c8);
    kr1 = *(const uint4*)(Khead + (size_t)(r8+32)*D_ + c8);
    vr0 = *(const uint4*)(Vh0 + (size_t)(r8   )*S_ + c8);
    vr1 = *(const uint4*)(Vh0 + (size_t)(r8+32)*S_ + c8);
  }

  #pragma unroll 1
  for (int phase=0; phase<2; phase++){
    const unsigned short* Vhead = phase ? Vh1 : Vh0;
    lac[0]=0.f; lac[1]=0.f;
    #pragma unroll
    for (int gg=0;gg<2;gg++)
      #pragma unroll
      for (int t=0;t<4;t++) oacc[gg][t]=fz;

    for (int kt=0; kt<S_; kt+=64){
      __syncthreads();
      *(uint4*)(&sK[chf][(r8   )*SD_ + co]) = kr0;
      *(uint4*)(&sK[chf][(r8+32)*SD_ + co]) = kr1;
      *(uint4*)(&sV[chf][(r8   )*SD_ + co]) = vr0;
      *(uint4*)(&sV[chf][(r8+32)*SD_ + co]) = vr1;
      __syncthreads();

      // prefetch next tile (next kt, or next phase's kt=0)
      {
        int nkt = kt + 64;
        const unsigned short* Vn = Vhead;
        if (nkt >= S_){ nkt = 0; Vn = Vh1; }
        kr0 = *(const uint4*)(Khead + (size_t)(nkt+r8   )*D_ + c8);
        kr1 = *(const uint4*)(Khead + (size_t)(nkt+r8+32)*D_ + c8);
        vr0 = *(const uint4*)(Vn + (size_t)(r8   )*S_ + nkt + c8);
        vr1 = *(const uint4*)(Vn + (size_t)(r8+32)*S_ + nkt + c8);
      }

      // S^T strip: 64 keys x 32 q per wave. A=K-frag, B=Q-frag.
      f32x4 sc[2][4];
      #pragma unroll
      for (int st=0; st<4; st++){
        short8 kA0 = *(const short8*)(&sK[0][(st*16+lr)*SD_ + qd*8]);
        short8 kA1 = *(const short8*)(&sK[1][(st*16+lr)*SD_ + qd*8]);
        #pragma unroll
        for (int gg=0; gg<2; gg++){
          f32x4 z = fz;
          z = __builtin_amdgcn_mfma_f32_16x16x32_bf16(kA0, qf[gg][0], z, 0,0,0);
          z = __builtin_amdgcn_mfma_f32_16x16x32_bf16(kA1, qf[gg][1], z, 0,0,0);
          sc[gg][st] = z;
        }
      }
      // HW exp2 + VALU row-sum + gg-sequential P round-trip
      short8 pf[2][2];
      #pragma unroll
      for (int gg=0; gg<2; gg++){
        #pragma unroll
        for (int st=0; st<4; st++){
          float p0=__builtin_amdgcn_exp2f(sc[gg][st][0]);
          float p1=__builtin_amdgcn_exp2f(sc[gg][st][1]);
          float p2=__builtin_amdgcn_exp2f(sc[gg][st][2]);
          float p3=__builtin_amdgcn_exp2f(sc[gg][st][3]);
          lac[gg] += (p0+p1)+(p2+p3);
          uint2 pk; pk.x = pk2bft(p0,p1); pk.y = pk2bft(p2,p3);
          unsigned short* Ph = (st&2) ? Pw1 : Pw0;
          *(uint2*)(Ph + lr*SD_ + (st&1)*16 + qd*4) = pk;
        }
        pf[gg][0] = *(const short8*)(Pw0 + lr*SD_ + qd*8);
        pf[gg][1] = *(const short8*)(Pw1 + lr*SD_ + qd*8);
      }
      // O^T += V^T-frag * P-frag
      #pragma unroll
      for (int dt=0; dt<4; dt++){
        short8 vA0 = *(const short8*)(&sV[0][(dt*16+lr)*SD_ + qd*8]);
        short8 vA1 = *(const short8*)(&sV[1][(dt*16+lr)*SD_ + qd*8]);
        #pragma unroll
        for (int gg=0; gg<2; gg++){
          oacc[gg][dt] = __builtin_amdgcn_mfma_f32_16x16x32_bf16(vA0, pf[gg][0], oacc[gg][dt], 0,0,0);
          oacc[gg][dt] = __builtin_amdgcn_mfma_f32_16x16x32_bf16(vA1, pf[gg][1], oacc[gg][dt], 0,0,0);
        }
      }
    } // kt

    #pragma unroll
    for (int gg=0;gg<2;gg++){
      lac[gg] += __shfl_xor(lac[gg], 16, 64);
      lac[gg] += __shfl_xor(lac[gg], 32, 64);
    }

    if (phase==0){
      // q2 = O^T/l * CE -> new Q fragments, gg-sequential through sP
      #pragma unroll
      for (int gg=0;gg<2;gg++){
        float iv = CE_ * __builtin_amdgcn_rcpf(lac[gg]);
        #pragma unroll
        for (int dt=0;dt<4;dt++){
          uint2 pk;
          pk.x = pk2bf(oacc[gg][dt][0]*iv, oacc[gg][dt][1]*iv);
          pk.y = pk2bf(oacc[gg][dt][2]*iv, oacc[gg][dt][3]*iv);
          unsigned short* Ph = (dt&2) ? Pw1 : Pw0;
          *(uint2*)(Ph + lr*SD_ + (dt&1)*16 + qd*4) = pk;
        }
        qf[gg][0] = *(const short8*)(Pw0 + lr*SD_ + qd*8);
        qf[gg][1] = *(const short8*)(Pw1 + lr*SD_ + qd*8);
      }
    } else {
      #pragma unroll
      for (int gg=0;gg<2;gg++){
        float iv = __builtin_amdgcn_rcpf(lac[gg]);
        unsigned short* Ob = QO + (size_t)(qt*128 + w*32 + gg*16 + lr)*D_ + h*64;
        #pragma unroll
        for (int dt=0;dt<4;dt++){
          uint2 pk;
          pk.x = pk2bf(oacc[gg][dt][0]*iv, oacc[gg][dt][1]*iv);
          pk.y = pk2bf(oacc[gg][dt][2]*iv, oacc[gg][dt][3]*iv);
          *(uint2*)(Ob + dt*16 + qd*4) = pk;
        }
      }
    }
  } // phase
}

// ---------------------------------------------------------------------------
extern "C" void kernel_launch(void* const* d_in, const int* in_sizes, int n_in,
                              void* d_out, int out_size, void* d_ws, size_t ws_size,
                              hipStream_t stream){
  const float* data = (const float*)d_in[0];
  const float* g_k  = (const float*)d_in[1];
  const float* b_k  = (const float*)d_in[2];
  const float* g_q  = (const float*)d_in[3];
  const float* b_q  = (const float*)d_in[4];
  const float* g_v  = (const float*)d_in[5];
  const float* b_v  = (const float*)d_in[6];
  const float* Wq   = (const float*)d_in[7];
  const float* bq   = (const float*)d_in[8];
  const float* Wk   = (const float*)d_in[9];
  const float* bk   = (const float*)d_in[10];
  const float* Wv   = (const float*)d_in[11];
  const float* bv   = (const float*)d_in[12];
  const float* Wo   = (const float*)d_in[13];
  const float* bo   = (const float*)d_in[14];
  float* out = (float*)d_out;

  char* ws = (char*)d_ws;
  const size_t MB = (size_t)1<<20;
  unsigned short* q    = (unsigned short*)(ws);
  unsigned short* kb   = (unsigned short*)(ws + 8*MB);
  unsigned short* WT   = (unsigned short*)(ws + 16*MB);
  unsigned short* WTo  = WT + ((size_t)3<<20);
  float*          bfld = (float*)(ws + 24*MB);
  float*          mean = bfld + 3*D_;
  float*          rstd = mean + M_;
  unsigned short* vT   = (unsigned short*)d_out;
  unsigned short* kT   = (unsigned short*)((char*)d_out + 8*MB);

  dim3 gb(256);
  prep_kernel<<<dim3(2096), gb, 0, stream>>>(data, mean, rstd,
                                             Wq, Wk, Wv, Wo, g_q, g_k, g_v,
                                             b_q, b_k, b_v, bq, bk, bv, WT, bfld);
  gemm_qkv<<<dim3(32,8,3), gb, 0, stream>>>(data, WT, bfld, mean, rstd, q, kb, kT, vT);
  attn_fused<<<dim3(32, H_), gb, 0, stream>>>(q, kb, kT, vT);
  gemm_out<<<dim3(32,8), gb, 0, stream>>>(q, WTo, bo, out);
}

// Round 13
// 266.754 us; speedup vs baseline: 1.0398x; 1.0398x over previous
//
#include <hip/hip_runtime.h>
#include <hip/hip_bf16.h>

// Problem constants
#define B_  2
#define S_  2048
#define D_  1024
#define H_  16
#define HD_ 64
#define M_  4096   // B_*S_

// Inputs/outputs f32; internal compute bf16 MFMA with f32 accumulation.
// ws (32 MB + 12 KB):
//   [0,8)MB  q bf16 (CE-prescaled via WTq/biasf; attn in-place)
//   [8,16)MB kb bf16
//   [16,24)MB WT bf16: 4 x [1024][1024] ([q CE*g | k g | v g | o plain])
//   [24,32)MB xhat bf16 [4096][1024]  (LN(data), affine folded into WT/biasf)
//   +32MB: biasf f32[3][1024]
// d_out (16 MB f32) as scratch until the final GEMM:
//   [0,8)MB vT bf16 [bh][d][s]   [8,16)MB kT bf16 [bh][d][s]
// gemm_out reads q + WT[o] (ws), writes d_out directly (vT/kT dead).
// NOTE: ws_size >= 32MB assumed; earlier "ws too small" NaNs were retro-
// attributed to the f32-read-as-bf16 dtype bug (rounds 1-3), not ws size.

typedef __attribute__((ext_vector_type(8))) short short8;
typedef __attribute__((ext_vector_type(4))) float f32x4;

#define CE_ 0.1803368801111204f   // 0.125 * log2(e)
#define SD_ 56                    // padded LDS row stride (shorts), attn only

typedef __attribute__((address_space(1))) const unsigned GU;
typedef __attribute__((address_space(3))) unsigned LU;
static __device__ __forceinline__ void glds16(const void* g, void* l){
  __builtin_amdgcn_global_load_lds((GU*)g, (LU*)l, 16, 0, 0);
}

static __device__ __forceinline__ unsigned short f2bfc(float f){
  union{float f; unsigned u;} c; c.f = f;
  return (unsigned short)((c.u + 0x8000u) >> 16);
}
static __device__ __forceinline__ unsigned pk2bf(float a, float b){
  union{float f; unsigned u;} ca, cb; ca.f=a; cb.f=b;
  return __builtin_amdgcn_perm(cb.u + 0x8000u, ca.u + 0x8000u, 0x07060302u);
}
static __device__ __forceinline__ unsigned pk2bft(float a, float b){
  union{float f; unsigned u;} ca, cb; ca.f=a; cb.f=b;
  return __builtin_amdgcn_perm(cb.u, ca.u, 0x07060302u);
}

// ---------------------------------------------------------------------------
// Merged prep: [0,1024) wtrans ; [1024,2048) xhat (stats+normalize fused,
// one row per wave — self-contained, no cross-block ordering) ; [2048,2096)
// biasfold.
// ---------------------------------------------------------------------------
__global__ __launch_bounds__(256) void prep_kernel(
  const float* __restrict__ data,
  const float* __restrict__ Wq, const float* __restrict__ Wk,
  const float* __restrict__ Wv, const float* __restrict__ Wo,
  const float* __restrict__ gq, const float* __restrict__ gk, const float* __restrict__ gv,
  const float* __restrict__ blq, const float* __restrict__ blk, const float* __restrict__ blv,
  const float* __restrict__ bpq, const float* __restrict__ bpk, const float* __restrict__ bpv,
  unsigned short* __restrict__ WT, unsigned short* __restrict__ xhat,
  float* __restrict__ bf)
{
  __shared__ unsigned short tile[64][72];
  __shared__ float red[4][64];
  int bid = blockIdx.x, t = threadIdx.x;
  if (bid < 1024){
    // --- weight transpose + cast: WT[z][n][k] = scale_z[k] * W_z[k][n] ---
    int z = bid >> 8, rem = bid & 255;
    int k0 = (rem>>4)*64, n0 = (rem&15)*64;
    const float* W = (z==0)?Wq:(z==1)?Wk:(z==2)?Wv:Wo;
    const float* g = (z==0)?gq:(z==1)?gk:(z==2)?gv:(const float*)0;
    unsigned short* out = WT + ((size_t)z<<20);
    {
      int kr = t>>2, c16 = (t&3)*16;
      float gs = g ? g[k0+kr]*((z==0)?CE_:1.0f) : 1.0f;
      const float* src = W + (size_t)(k0+kr)*D_ + n0 + c16;
      float4 w0 = *(const float4*)(src);
      float4 w1 = *(const float4*)(src+4);
      float4 w2 = *(const float4*)(src+8);
      float4 w3 = *(const float4*)(src+12);
      unsigned* tp = (unsigned*)&tile[kr][c16];
      tp[0]=pk2bf(w0.x*gs,w0.y*gs); tp[1]=pk2bf(w0.z*gs,w0.w*gs);
      tp[2]=pk2bf(w1.x*gs,w1.y*gs); tp[3]=pk2bf(w1.z*gs,w1.w*gs);
      tp[4]=pk2bf(w2.x*gs,w2.y*gs); tp[5]=pk2bf(w2.z*gs,w2.w*gs);
      tp[6]=pk2bf(w3.x*gs,w3.y*gs); tp[7]=pk2bf(w3.z*gs,w3.w*gs);
    }
    __syncthreads();
    {
      int nr = t>>2, kc = (t&3)*16;
      union { uint4 v[2]; unsigned short u[16]; } st;
      #pragma unroll
      for (int i=0;i<16;i++) st.u[i] = tile[kc+i][nr];
      unsigned short* dst = out + (size_t)(n0+nr)*D_ + k0 + kc;
      *(uint4*)(dst)     = st.v[0];
      *(uint4*)(dst + 8) = st.v[1];
    }
  } else if (bid < 2048){
    // --- xhat: one row per wave, stats + normalize + bf16 store ---
    int row = (bid-1024)*4 + (t>>6);
    int l = t & 63;
    const float4* xr = (const float4*)(data + (size_t)row*D_);
    float4 v[4];
    float s = 0.f, ss = 0.f;
    #pragma unroll
    for (int i=0;i<4;i++){
      v[i] = xr[l + 64*i];
      s  += v[i].x+v[i].y+v[i].z+v[i].w;
      ss += v[i].x*v[i].x+v[i].y*v[i].y+v[i].z*v[i].z+v[i].w*v[i].w;
    }
    #pragma unroll
    for (int m=1;m<64;m<<=1){ s += __shfl_xor(s, m, 64); ss += __shfl_xor(ss, m, 64); }
    float me = s*(1.0f/D_);
    float var = ss*(1.0f/D_) - me*me;
    float rs = rsqrtf(var + 1e-5f);
    float nm = -me*rs;
    unsigned short* xo = xhat + (size_t)row*D_;
    #pragma unroll
    for (int i=0;i<4;i++){
      uint2 pk;
      pk.x = pk2bf(fmaf(v[i].x,rs,nm), fmaf(v[i].y,rs,nm));
      pk.y = pk2bf(fmaf(v[i].z,rs,nm), fmaf(v[i].w,rs,nm));
      *(uint2*)(xo + 4*l + 256*i) = pk;
    }
  } else {
    // --- folded bias ---
    int idx = bid - 2048;
    int z = idx >> 4, xb = idx & 15;
    const float* W  = (z==0)?Wq:(z==1)?Wk:Wv;
    const float* bl = (z==0)?blq:(z==1)?blk:blv;
    const float* bp = (z==0)?bpq:(z==1)?bpk:bpv;
    int nl = t & 63, kg = t >> 6;
    int n = xb*64 + nl;
    float acc = 0.f;
    for (int k = kg*256; k < (kg+1)*256; k++)
      acc += bl[k] * W[(size_t)k*D_ + n];
    red[kg][nl] = acc;
    __syncthreads();
    if (t < 64){
      int nn = xb*64 + t;
      float v = red[0][t]+red[1][t]+red[2][t]+red[3][t] + bp[nn];
      bf[z*D_ + nn] = (z==0) ? v*CE_ : v;
    }
  }
}

// ---------------------------------------------------------------------------
// Fused QKV GEMM, grid (32,8,3). 128x128 tile. Both tiles via glds width=16
// (A from precomputed bf16 xhat), unpadded stride-32 LDS.
// ---------------------------------------------------------------------------
__global__ __launch_bounds__(256) void gemm_qkv(
  const unsigned short* __restrict__ xhat,
  const unsigned short* __restrict__ WT,
  const float* __restrict__ biasf,
  unsigned short* __restrict__ qv, unsigned short* __restrict__ kb,
  unsigned short* __restrict__ kT, unsigned short* __restrict__ vT)
{
  int z = blockIdx.z;
  const unsigned short* Bt = WT + ((size_t)z<<20);
  const float* bias = biasf + z*D_;
  unsigned short* oN = (z==0)?qv:(z==1)?kb:(unsigned short*)0;
  unsigned short* oT = (z==0)?(unsigned short*)0:(z==1)?kT:vT;

  __shared__ __align__(16) unsigned short As[128*32];
  __shared__ __align__(16) unsigned short Bs[128*32];
  int tid = threadIdx.x, w = tid>>6, l = tid&63;
  int m0 = blockIdx.x*128, n0 = blockIdx.y*128;
  int wr = (w>>1)*64, wc = (w&1)*64;
  int lr = l&15, qd = l>>4;

  const unsigned short* gA = xhat + (size_t)(m0 + w*32 + (l>>2))*D_ + (l&3)*8;
  const unsigned short* gB = Bt   + (size_t)(n0 + w*32 + (l>>2))*D_ + (l&3)*8;
  unsigned short* lA0 = &As[(w*32)*32];
  unsigned short* lA1 = &As[(w*32+16)*32];
  unsigned short* lB0 = &Bs[(w*32)*32];
  unsigned short* lB1 = &Bs[(w*32+16)*32];

  const f32x4 fz = {0.f,0.f,0.f,0.f};
  f32x4 acc[4][4];
  #pragma unroll
  for (int i=0;i<4;i++)
    #pragma unroll
    for (int j=0;j<4;j++) acc[i][j] = fz;

  for (int kk=0; kk<D_; kk+=32){
    __syncthreads();
    glds16(gA + kk,                 lA0);
    glds16(gA + kk + (size_t)16*D_, lA1);
    glds16(gB + kk,                 lB0);
    glds16(gB + kk + (size_t)16*D_, lB1);
    __syncthreads();
    short8 af[4], bfr[4];
    #pragma unroll
    for (int i=0;i<4;i++) af[i]  = *(const short8*)(As + (wr + i*16 + lr)*32 + qd*8);
    #pragma unroll
    for (int j=0;j<4;j++) bfr[j] = *(const short8*)(Bs + (wc + j*16 + lr)*32 + qd*8);
    #pragma unroll
    for (int i=0;i<4;i++)
      #pragma unroll
      for (int j=0;j<4;j++)
        acc[i][j] = __builtin_amdgcn_mfma_f32_16x16x32_bf16(af[i], bfr[j], acc[i][j], 0, 0, 0);
  }

  #pragma unroll
  for (int j=0;j<4;j++){
    int n = n0 + wc + j*16 + lr;
    float bias_n = bias[n];
    #pragma unroll
    for (int i=0;i<4;i++){
      int mb = m0 + wr + i*16 + qd*4;
      float v0 = acc[i][j][0] + bias_n;
      float v1 = acc[i][j][1] + bias_n;
      float v2 = acc[i][j][2] + bias_n;
      float v3 = acc[i][j][3] + bias_n;
      if (oN){
        oN[(size_t)(mb+0)*D_ + n] = f2bfc(v0);
        oN[(size_t)(mb+1)*D_ + n] = f2bfc(v1);
        oN[(size_t)(mb+2)*D_ + n] = f2bfc(v2);
        oN[(size_t)(mb+3)*D_ + n] = f2bfc(v3);
      }
      if (oT){
        int bb = mb >> 11, sI = mb & (S_-1);
        int hh = n >> 6,  dd = n & 63;
        uint2 pk; pk.x = pk2bf(v0, v1); pk.y = pk2bf(v2, v3);
        *(uint2*)(oT + (size_t)((bb*H_ + hh)*HD_ + dd)*S_ + sI) = pk;
      }
    }
  }
}

// ---------------------------------------------------------------------------
// Out-projection: C = A(bf16) @ WTo^T + bo, f32 to d_out. Both tiles via glds.
// ---------------------------------------------------------------------------
__global__ __launch_bounds__(256) void gemm_out(
  const unsigned short* __restrict__ A,
  const unsigned short* __restrict__ Bt,
  const float* __restrict__ bo,
  float* __restrict__ Cf)
{
  __shared__ __align__(16) unsigned short As[128*32];
  __shared__ __align__(16) unsigned short Bs[128*32];
  int tid = threadIdx.x, w = tid>>6, l = tid&63;
  int m0 = blockIdx.x*128, n0 = blockIdx.y*128;
  int wr = (w>>1)*64, wc = (w&1)*64;
  int lr = l&15, qd = l>>4;

  const unsigned short* gA = A  + (size_t)(m0 + w*32 + (l>>2))*D_ + (l&3)*8;
  const unsigned short* gB = Bt + (size_t)(n0 + w*32 + (l>>2))*D_ + (l&3)*8;
  unsigned short* lA0 = &As[(w*32)*32];
  unsigned short* lA1 = &As[(w*32+16)*32];
  unsigned short* lB0 = &Bs[(w*32)*32];
  unsigned short* lB1 = &Bs[(w*32+16)*32];

  const f32x4 fz = {0.f,0.f,0.f,0.f};
  f32x4 acc[4][4];
  #pragma unroll
  for (int i=0;i<4;i++)
    #pragma unroll
    for (int j=0;j<4;j++) acc[i][j] = fz;

  for (int kk=0; kk<D_; kk+=32){
    __syncthreads();
    glds16(gA + kk,                 lA0);
    glds16(gA + kk + (size_t)16*D_, lA1);
    glds16(gB + kk,                 lB0);
    glds16(gB + kk + (size_t)16*D_, lB1);
    __syncthreads();
    short8 af[4], bfr[4];
    #pragma unroll
    for (int i=0;i<4;i++) af[i]  = *(const short8*)(As + (wr + i*16 + lr)*32 + qd*8);
    #pragma unroll
    for (int j=0;j<4;j++) bfr[j] = *(const short8*)(Bs + (wc + j*16 + lr)*32 + qd*8);
    #pragma unroll
    for (int i=0;i<4;i++)
      #pragma unroll
      for (int j=0;j<4;j++)
        acc[i][j] = __builtin_amdgcn_mfma_f32_16x16x32_bf16(af[i], bfr[j], acc[i][j], 0, 0, 0);
  }

  #pragma unroll
  for (int j=0;j<4;j++){
    int n = n0 + wc + j*16 + lr;
    float bias_n = bo[n];
    #pragma unroll
    for (int i=0;i<4;i++){
      int mb = m0 + wr + i*16 + qd*4;
      Cf[(size_t)(mb+0)*D_ + n] = acc[i][j][0] + bias_n;
      Cf[(size_t)(mb+1)*D_ + n] = acc[i][j][1] + bias_n;
      Cf[(size_t)(mb+2)*D_ + n] = acc[i][j][2] + bias_n;
      Cf[(size_t)(mb+3)*D_ + n] = acc[i][j][3] + bias_n;
    }
  }
}

// ---------------------------------------------------------------------------
// Fused double Hopfield attention (round-12 proven): transposed compute
// (S^T/O^T), in-place on QO (bf16, CE-prescaled), gg-sequential sP,
// BK=64, one-tile register prefetch, HW exp2, VALU row-sum. grid (32,16).
// ---------------------------------------------------------------------------
__global__ __launch_bounds__(256) void attn_fused(
  unsigned short* __restrict__ QO,
  const unsigned short* __restrict__ K,
  const unsigned short* __restrict__ KT,
  const unsigned short* __restrict__ VT)
{
  int qt = blockIdx.x;           // 0..31
  int h  = blockIdx.y;           // 0..15
  int b  = qt >> 4;
  int bh = b*H_ + h;
  int tid = threadIdx.x, w = tid>>6, l = tid&63;
  int lr = l&15, qd = l>>4;
  int r8 = tid>>3, c8 = (tid&7)*8;
  int chf = c8>>5, co = c8&31;

  __shared__ __align__(16) unsigned short sK[2][64*SD_];
  __shared__ __align__(16) unsigned short sV[2][64*SD_];
  __shared__ __align__(16) unsigned short sP[4][2][16*SD_];  // gg-sequential

  const f32x4 fz = {0.f,0.f,0.f,0.f};

  unsigned short* Qbase = QO + (size_t)(qt*128 + w*32) * D_ + h*64;
  short8 qf[2][2];
  #pragma unroll
  for (int gg=0; gg<2; gg++)
    #pragma unroll
    for (int hf=0; hf<2; hf++)
      qf[gg][hf] = *(const short8*)(Qbase + (size_t)(gg*16+lr)*D_ + hf*32 + qd*8);

  const unsigned short* Khead = K + (size_t)(b*S_)*D_ + h*64;
  const unsigned short* Vh0 = KT + (size_t)bh*HD_*S_;
  const unsigned short* Vh1 = VT + (size_t)bh*HD_*S_;
  unsigned short* Pw0 = &sP[w][0][0];
  unsigned short* Pw1 = &sP[w][1][0];

  f32x4 oacc[2][4];
  float lac[2];

  uint4 kr0, kr1, vr0, vr1;
  {
    kr0 = *(const uint4*)(Khead + (size_t)(r8   )*D_ + c8);
    kr1 = *(const uint4*)(Khead + (size_t)(r8+32)*D_ + c8);
    vr0 = *(const uint4*)(Vh0 + (size_t)(r8   )*S_ + c8);
    vr1 = *(const uint4*)(Vh0 + (size_t)(r8+32)*S_ + c8);
  }

  #pragma unroll 1
  for (int phase=0; phase<2; phase++){
    const unsigned short* Vhead = phase ? Vh1 : Vh0;
    lac[0]=0.f; lac[1]=0.f;
    #pragma unroll
    for (int gg=0;gg<2;gg++)
      #pragma unroll
      for (int t=0;t<4;t++) oacc[gg][t]=fz;

    for (int kt=0; kt<S_; kt+=64){
      __syncthreads();
      *(uint4*)(&sK[chf][(r8   )*SD_ + co]) = kr0;
      *(uint4*)(&sK[chf][(r8+32)*SD_ + co]) = kr1;
      *(uint4*)(&sV[chf][(r8   )*SD_ + co]) = vr0;
      *(uint4*)(&sV[chf][(r8+32)*SD_ + co]) = vr1;
      __syncthreads();

      {
        int nkt = kt + 64;
        const unsigned short* Vn = Vhead;
        if (nkt >= S_){ nkt = 0; Vn = Vh1; }
        kr0 = *(const uint4*)(Khead + (size_t)(nkt+r8   )*D_ + c8);
        kr1 = *(const uint4*)(Khead + (size_t)(nkt+r8+32)*D_ + c8);
        vr0 = *(const uint4*)(Vn + (size_t)(r8   )*S_ + nkt + c8);
        vr1 = *(const uint4*)(Vn + (size_t)(r8+32)*S_ + nkt + c8);
      }

      f32x4 sc[2][4];
      #pragma unroll
      for (int st=0; st<4; st++){
        short8 kA0 = *(const short8*)(&sK[0][(st*16+lr)*SD_ + qd*8]);
        short8 kA1 = *(const short8*)(&sK[1][(st*16+lr)*SD_ + qd*8]);
        #pragma unroll
        for (int gg=0; gg<2; gg++){
          f32x4 z = fz;
          z = __builtin_amdgcn_mfma_f32_16x16x32_bf16(kA0, qf[gg][0], z, 0,0,0);
          z = __builtin_amdgcn_mfma_f32_16x16x32_bf16(kA1, qf[gg][1], z, 0,0,0);
          sc[gg][st] = z;
        }
      }
      short8 pf[2][2];
      #pragma unroll
      for (int gg=0; gg<2; gg++){
        #pragma unroll
        for (int st=0; st<4; st++){
          float p0=__builtin_amdgcn_exp2f(sc[gg][st][0]);
          float p1=__builtin_amdgcn_exp2f(sc[gg][st][1]);
          float p2=__builtin_amdgcn_exp2f(sc[gg][st][2]);
          float p3=__builtin_amdgcn_exp2f(sc[gg][st][3]);
          lac[gg] += (p0+p1)+(p2+p3);
          uint2 pk; pk.x = pk2bft(p0,p1); pk.y = pk2bft(p2,p3);
          unsigned short* Ph = (st&2) ? Pw1 : Pw0;
          *(uint2*)(Ph + lr*SD_ + (st&1)*16 + qd*4) = pk;
        }
        pf[gg][0] = *(const short8*)(Pw0 + lr*SD_ + qd*8);
        pf[gg][1] = *(const short8*)(Pw1 + lr*SD_ + qd*8);
      }
      #pragma unroll
      for (int dt=0; dt<4; dt++){
        short8 vA0 = *(const short8*)(&sV[0][(dt*16+lr)*SD_ + qd*8]);
        short8 vA1 = *(const short8*)(&sV[1][(dt*16+lr)*SD_ + qd*8]);
        #pragma unroll
        for (int gg=0; gg<2; gg++){
          oacc[gg][dt] = __builtin_amdgcn_mfma_f32_16x16x32_bf16(vA0, pf[gg][0], oacc[gg][dt], 0,0,0);
          oacc[gg][dt] = __builtin_amdgcn_mfma_f32_16x16x32_bf16(vA1, pf[gg][1], oacc[gg][dt], 0,0,0);
        }
      }
    } // kt

    #pragma unroll
    for (int gg=0;gg<2;gg++){
      lac[gg] += __shfl_xor(lac[gg], 16, 64);
      lac[gg] += __shfl_xor(lac[gg], 32, 64);
    }

    if (phase==0){
      #pragma unroll
      for (int gg=0;gg<2;gg++){
        float iv = CE_ * __builtin_amdgcn_rcpf(lac[gg]);
        #pragma unroll
        for (int dt=0;dt<4;dt++){
          uint2 pk;
          pk.x = pk2bf(oacc[gg][dt][0]*iv, oacc[gg][dt][1]*iv);
          pk.y = pk2bf(oacc[gg][dt][2]*iv, oacc[gg][dt][3]*iv);
          unsigned short* Ph = (dt&2) ? Pw1 : Pw0;
          *(uint2*)(Ph + lr*SD_ + (dt&1)*16 + qd*4) = pk;
        }
        qf[gg][0] = *(const short8*)(Pw0 + lr*SD_ + qd*8);
        qf[gg][1] = *(const short8*)(Pw1 + lr*SD_ + qd*8);
      }
    } else {
      #pragma unroll
      for (int gg=0;gg<2;gg++){
        float iv = __builtin_amdgcn_rcpf(lac[gg]);
        unsigned short* Ob = QO + (size_t)(qt*128 + w*32 + gg*16 + lr)*D_ + h*64;
        #pragma unroll
        for (int dt=0;dt<4;dt++){
          uint2 pk;
          pk.x = pk2bf(oacc[gg][dt][0]*iv, oacc[gg][dt][1]*iv);
          pk.y = pk2bf(oacc[gg][dt][2]*iv, oacc[gg][dt][3]*iv);
          *(uint2*)(Ob + dt*16 + qd*4) = pk;
        }
      }
    }
  } // phase
}

// ---------------------------------------------------------------------------
extern "C" void kernel_launch(void* const* d_in, const int* in_sizes, int n_in,
                              void* d_out, int out_size, void* d_ws, size_t ws_size,
                              hipStream_t stream){
  const float* data = (const float*)d_in[0];
  const float* g_k  = (const float*)d_in[1];
  const float* b_k  = (const float*)d_in[2];
  const float* g_q  = (const float*)d_in[3];
  const float* b_q  = (const float*)d_in[4];
  const float* g_v  = (const float*)d_in[5];
  const float* b_v  = (const float*)d_in[6];
  const float* Wq   = (const float*)d_in[7];
  const float* bq   = (const float*)d_in[8];
  const float* Wk   = (const float*)d_in[9];
  const float* bk   = (const float*)d_in[10];
  const float* Wv   = (const float*)d_in[11];
  const float* bv   = (const float*)d_in[12];
  const float* Wo   = (const float*)d_in[13];
  const float* bo   = (const float*)d_in[14];
  float* out = (float*)d_out;

  char* ws = (char*)d_ws;
  const size_t MB = (size_t)1<<20;
  unsigned short* q    = (unsigned short*)(ws);
  unsigned short* kb   = (unsigned short*)(ws + 8*MB);
  unsigned short* WT   = (unsigned short*)(ws + 16*MB);
  unsigned short* WTo  = WT + ((size_t)3<<20);
  unsigned short* xhat = (unsigned short*)(ws + 24*MB);
  float*          bfld = (float*)(ws + 32*MB);
  unsigned short* vT   = (unsigned short*)d_out;
  unsigned short* kT   = (unsigned short*)((char*)d_out + 8*MB);

  dim3 gb(256);
  prep_kernel<<<dim3(2096), gb, 0, stream>>>(data,
                                             Wq, Wk, Wv, Wo, g_q, g_k, g_v,
                                             b_q, b_k, b_v, bq, bk, bv,
                                             WT, xhat, bfld);
  gemm_qkv<<<dim3(32,8,3), gb, 0, stream>>>(xhat, WT, bfld, q, kb, kT, vT);
  attn_fused<<<dim3(32, H_), gb, 0, stream>>>(q, kb, kT, vT);
  gemm_out<<<dim3(32,8), gb, 0, stream>>>(q, WTo, bo, out);
}